// Round 8
// baseline (246.978 us; speedup 1.0000x reference)
//
#include <hip/hip_runtime.h>
#include <hip/hip_fp16.h>

#define EMB_D 64
#define SB 1024     // scan block size
#define SPAN 128    // nodes per group (pow2: group = dst>>7, local = dst&127)
#define MAXG 1024   // max groups for LDS arrays
#define NCHUNK2 512 // edge chunks
#define CHMAX 4096  // max edges per chunk for LDS record buffer (32 KB)
#define TILE 4096   // gather tile (records)
#define SLICE_SH 14 // src-slice: 16384 rows = 2 MB of emb16 per slice
#define MAXS 8      // max slices (N < 131072)
#define SKEYBINS (MAXS * SPAN)
#define CAST_BLOCKS 256

// ===========================================================================
// Tier A8: A6 front-end (proven) + slice-phased gather with soft grid sync.
//   A1 : fused fp16 cast + per-chunk group histogram (LDS atomics)
//   scan: 3-phase over [G][NCHUNK2] -> per-(chunk,group) global bases
//   PS : per-chunk LDS counting sort -> stream8 (group-contiguous)
//   GS : gather_sliced: block per group; LDS-sorts its segment by
//        (src-slice, node) [640 bins]; then S phases, one 2MB slice each,
//        separated by a SOFT global barrier (atomic arrive + bounded spin).
//        All 554 blocks co-resident (29KB LDS, 4 blk/CU cap) -> per-XCD
//        row working set 2MB = L2-resident. Barrier is perf-only: timeout
//        -> proceed; correctness never depends on co-residency (G16).
// Tier A6: same front-end + unsliced gather_fused (proven 175 us).
// Tier C : atomic scatter fallback.
// R4: LDS-atomic accumulate ~100x too slow. R6: gather L2-miss-bound.
// R7: UNSYNCED slice phasing is useless (blocks drift); global slice-sort
//     costs +30us front-end. Hence: local slice-sort + enforced phasing.
// ===========================================================================

__device__ __forceinline__ float h15_to_float(unsigned int bits) {
    return __half2float(__ushort_as_half((unsigned short)bits));
}

// --- A1: fused cast + chunked group histogram (no global atomics) ---------
__global__ void a1_cast_hist(const float2* __restrict__ embin,
                             __half2* __restrict__ emb16, int n2,
                             const int* __restrict__ dst,
                             int* __restrict__ cntT,   // [G][NCHUNK2]
                             int E, int G, int chunk) {
    if (blockIdx.x < CAST_BLOCKS) {
        int i = blockIdx.x * blockDim.x + threadIdx.x;
        int st = CAST_BLOCKS * blockDim.x;
        for (; i < n2; i += st)
            emb16[i] = __float22half2_rn(embin[i]);
    } else {
        __shared__ int bins[MAXG];
        int hb = blockIdx.x - CAST_BLOCKS;
        for (int g = threadIdx.x; g < G; g += blockDim.x) bins[g] = 0;
        __syncthreads();
        int beg = hb * chunk;
        int end = min(beg + chunk, E);
        for (int i = beg + threadIdx.x; i < end; i += blockDim.x)
            atomicAdd(&bins[dst[i] >> 7], 1);
        __syncthreads();
        for (int g = threadIdx.x; g < G; g += blockDim.x)
            cntT[g * NCHUNK2 + hb] = bins[g];
    }
}

// --- generic 3-phase exclusive scan ---------------------------------------
__global__ void scan_reduceB(const int* __restrict__ counts,
                             int* __restrict__ partial, int M) {
    __shared__ int wsum[16];
    const int tid = threadIdx.x, lane = tid & 63, wid = tid >> 6;
    int i = blockIdx.x * SB + tid;
    int v = (i < M) ? counts[i] : 0;
    #pragma unroll
    for (int off = 32; off > 0; off >>= 1)
        v += __shfl_xor(v, off, 64);
    if (lane == 0) wsum[wid] = v;
    __syncthreads();
    if (tid == 0) {
        int s = 0;
        #pragma unroll
        for (int k = 0; k < 16; ++k) s += wsum[k];
        partial[blockIdx.x] = s;
    }
}

__global__ void scan_partials(const int* __restrict__ partial,
                              int* __restrict__ blockoff,
                              int* __restrict__ offsets, int numB, int M) {
    __shared__ int wsum[16];
    __shared__ int wpre[16];
    __shared__ int carry;
    const int tid = threadIdx.x, lane = tid & 63, wid = tid >> 6;
    if (tid == 0) carry = 0;
    const int nPass = (numB + SB - 1) / SB;
    for (int p = 0; p < nPass; ++p) {
        __syncthreads();
        int base = carry;
        int idx = p * SB + tid;
        int v = (idx < numB) ? partial[idx] : 0;
        int x = v;
        #pragma unroll
        for (int off = 1; off < 64; off <<= 1) {
            int t = __shfl_up(x, off, 64);
            if (lane >= off) x += t;
        }
        if (lane == 63) wsum[wid] = x;
        __syncthreads();
        if (wid == 0) {
            int s = (lane < 16) ? wsum[lane] : 0;
            #pragma unroll
            for (int off = 1; off < 16; off <<= 1) {
                int t = __shfl_up(s, off, 64);
                if (lane >= off) s += t;
            }
            if (lane < 16) wpre[lane] = s;
        }
        __syncthreads();
        int excl = base + ((wid > 0) ? wpre[wid - 1] : 0) + (x - v);
        if (idx < numB) blockoff[idx] = excl;
        __syncthreads();
        if (tid == 0) carry = base + wpre[15];
    }
    __syncthreads();
    if (tid == 0) offsets[M] = carry;   // grand total = E
}

__global__ void scan_applyB(const int* __restrict__ counts,
                            const int* __restrict__ blockoff,
                            int* __restrict__ offsets, int M) {
    __shared__ int wsum[16];
    __shared__ int wpre[16];
    const int tid = threadIdx.x, lane = tid & 63, wid = tid >> 6;
    int i = blockIdx.x * SB + tid;
    int v = (i < M) ? counts[i] : 0;
    int x = v;
    #pragma unroll
    for (int off = 1; off < 64; off <<= 1) {
        int t = __shfl_up(x, off, 64);
        if (lane >= off) x += t;
    }
    if (lane == 63) wsum[wid] = x;
    __syncthreads();
    if (wid == 0) {
        int s = (lane < 16) ? wsum[lane] : 0;
        #pragma unroll
        for (int off = 1; off < 16; off <<= 1) {
            int t = __shfl_up(s, off, 64);
            if (lane >= off) s += t;
        }
        if (lane < 16) wpre[lane] = s;
    }
    __syncthreads();
    int excl = blockoff[blockIdx.x] + ((wid > 0) ? wpre[wid - 1] : 0) + (x - v);
    if (i < M) offsets[i] = excl;
}

// --- PS: per-chunk LDS counting sort + linear coalesced drain (512 thr) ---
__global__ __launch_bounds__(512) void partition_sort(
        const int* __restrict__ src,
        const int* __restrict__ dst,
        const float* __restrict__ w,
        const int* __restrict__ cntT,    // [G][NCHUNK2]
        const int* __restrict__ scanT,   // [G*NCHUNK2+1]
        uint2* __restrict__ stream8,     // [E]
        int E, int G, int chunk) {
    __shared__ uint2 recs[CHMAX];        // 32 KB
    __shared__ int cur[MAXG];
    __shared__ int delta[MAXG];
    __shared__ int wtot[8];

    const int tid = threadIdx.x, lane = tid & 63, wv = tid >> 6;
    const int b = blockIdx.x;
    const int beg = b * chunk;
    const int end = min(beg + chunk, E);
    const int n = end - beg;

    const int K = (G + 511) >> 9;        // <= 2
    int vals[2];
    int acc = 0;
    #pragma unroll
    for (int k = 0; k < 2; ++k) {
        int g = tid * K + k;
        int c = (k < K && g < G) ? cntT[g * NCHUNK2 + b] : 0;
        vals[k] = c;
        acc += c;
    }
    int x = acc;
    #pragma unroll
    for (int off = 1; off < 64; off <<= 1) {
        int t = __shfl_up(x, off, 64);
        if (lane >= off) x += t;
    }
    if (lane == 63) wtot[wv] = x;
    __syncthreads();
    int woff = 0;
    #pragma unroll
    for (int k2 = 0; k2 < 8; ++k2)
        woff += (k2 < wv) ? wtot[k2] : 0;
    int run = woff + x - acc;
    #pragma unroll
    for (int k = 0; k < 2; ++k) {
        int g = tid * K + k;
        if (k < K && g < G) {
            cur[g] = run;
            delta[g] = scanT[g * NCHUNK2 + b] - run;
            run += vals[k];
        }
    }
    __syncthreads();

    for (int i = beg + tid; i < end; i += 512) {
        int d = dst[i];
        unsigned int wb = __half_as_ushort(__float2half_rn(w[i]));
        unsigned int pk = ((unsigned int)src[i] << 15) | (wb & 0x7FFFu);
        int g = d >> 7;
        int j = atomicAdd(&cur[g], 1);
        recs[j] = make_uint2(pk, (unsigned int)(d & (SPAN - 1)) |
                                 ((unsigned int)g << 7));
    }
    __syncthreads();

    for (int j = tid; j < n; j += 512) {
        uint2 r = recs[j];
        int g = (int)(r.y >> 7);
        stream8[delta[g] + j] = make_uint2(r.x, r.y & (SPAN - 1u));
    }
}

// --- helpers for gather_sliced --------------------------------------------
// exclusive scan of NB (<=1024) LDS counters; thread t owns bins 2t,2t+1
__device__ __forceinline__ void bin_scan(int* hcnt, int* nstart, int* cur,
                                         int* wtot, int NB) {
    const int tid = threadIdx.x, lane = tid & 63, wv = tid >> 6;
    int b0 = tid << 1, b1 = b0 + 1;
    int v0 = (b0 < NB) ? hcnt[b0] : 0;
    int v1 = (b1 < NB) ? hcnt[b1] : 0;
    int p = v0 + v1;
    int x = p;
    #pragma unroll
    for (int off = 1; off < 64; off <<= 1) {
        int t = __shfl_up(x, off, 64);
        if (lane >= off) x += t;
    }
    if (lane == 63) wtot[wv] = x;
    __syncthreads();
    int woff = 0;
    #pragma unroll
    for (int k = 0; k < 8; ++k) woff += (k < wv) ? wtot[k] : 0;
    int excl = woff + x - p;
    if (b0 < NB) { nstart[b0] = excl; cur[b0] = excl; }
    if (b1 < NB) { nstart[b1] = excl + v0; cur[b1] = excl + v0; }
    __syncthreads();
}

// soft grid barrier: perf hint only; bounded spin -> never deadlocks.
__device__ __forceinline__ void soft_grid_sync(int* bar, int phase, int nblk) {
    __syncthreads();
    if (threadIdx.x == 0) {
        int want = nblk * (phase + 1);
        int got = atomicAdd(bar, 1) + 1;
        int spins = 0;
        while (got < want && spins < 1000) {
            __builtin_amdgcn_s_sleep(32);
            got = __hip_atomic_load(bar, __ATOMIC_RELAXED,
                                    __HIP_MEMORY_SCOPE_AGENT);
            ++spins;
        }
    }
    __syncthreads();
}

// --- GS: slice-phased fused gather ----------------------------------------
// Sort segment by (slice,node) in LDS; S phases (one 2MB src-slice each)
// with soft grid sync between -> per-XCD working set L2-resident.
// Crew = 16 lanes owns nodes {c,c+32,c+64,c+96}; two 8-lane substreams,
// uint4 rows, 2-deep each (R6 structure).
__global__ __launch_bounds__(512) void gather_sliced(
        const char* __restrict__ emb16b,      // row v at byte v*128
        const uint2* __restrict__ stream8,    // [E] {pk, dl}
        const int* __restrict__ scanT,        // [G*NCHUNK2+1]
        float* __restrict__ out, int N, int S, int* bar) {
    __shared__ unsigned int srt[TILE];        // 16 KB
    __shared__ int hcnt[SKEYBINS];            // 4 KB
    __shared__ int nstart[SKEYBINS];          // 4 KB
    __shared__ int cur[SKEYBINS];             // 4 KB
    __shared__ int wtot[8];

    const int g = blockIdx.x;
    const int tid = threadIdx.x;
    const int base = scanT[g * NCHUNK2];
    const int endE = scanT[(g + 1) * NCHUNK2];   // last group -> scanT[M]=E
    const int n = endE - base;
    const int crew = tid >> 4;                   // 0..31
    const int ql = tid & 15;
    const int sub = ql >> 3;                     // substream 0/1
    const int sl = ql & 7;                       // 16B segment of row
    const unsigned qlo = (unsigned)(sl << 4);
    const int nblk = gridDim.x;

    float4 accA[4], accB[4];                  // dims sl*16+sub*?: A=0..3,B=4..7 of lane's 8
    #pragma unroll
    for (int ni = 0; ni < 4; ++ni) {
        accA[ni] = make_float4(0.f, 0.f, 0.f, 0.f);
        accB[ni] = make_float4(0.f, 0.f, 0.f, 0.f);
    }

    if (n <= TILE) {
        // ---- sliced path: sort by (slice,node), then S phased walks ----
        const int NB = S * SPAN;
        for (int k = tid; k < NB; k += 512) hcnt[k] = 0;
        __syncthreads();
        for (int j = tid; j < n; j += 512) {
            uint2 r = stream8[base + j];
            int skey = (int)((r.x >> 15) >> SLICE_SH);
            atomicAdd(&hcnt[(skey << 7) + (int)r.y], 1);
        }
        __syncthreads();
        bin_scan(hcnt, nstart, cur, wtot, NB);
        for (int j = tid; j < n; j += 512) {        // L2-hot second read
            uint2 r = stream8[base + j];
            int skey = (int)((r.x >> 15) >> SLICE_SH);
            int slot = atomicAdd(&cur[(skey << 7) + (int)r.y], 1);
            srt[slot] = r.x;
        }
        __syncthreads();

        for (int s = 0; s < S; ++s) {
            #pragma unroll
            for (int ni = 0; ni < 4; ++ni) {
                int bin = (s << 7) + crew + (ni << 5);
                int sB = nstart[bin];
                int e = cur[bin];
                float4 aA = accA[ni];
                float4 aB = accB[ni];
                int k0 = sB + sub;
                unsigned int pk0 = (k0 < e) ? srt[k0] : 0u;
                uint4 r0 = *reinterpret_cast<const uint4*>(
                    emb16b + ((pk0 >> 15) * 128u + qlo));
                for (int k = k0; k < e; k += 2) {
                    int k1 = k + 2;
                    unsigned int pk1 = (k1 < e) ? srt[k1] : 0u;
                    uint4 r1 = *reinterpret_cast<const uint4*>(
                        emb16b + ((pk1 >> 15) * 128u + qlo));
                    float wt = h15_to_float(pk0 & 0x7FFFu);
                    float2 x01 = __half22float2(*reinterpret_cast<__half2*>(&r0.x));
                    float2 x23 = __half22float2(*reinterpret_cast<__half2*>(&r0.y));
                    float2 x45 = __half22float2(*reinterpret_cast<__half2*>(&r0.z));
                    float2 x67 = __half22float2(*reinterpret_cast<__half2*>(&r0.w));
                    aA.x = fmaf(x01.x, wt, aA.x);
                    aA.y = fmaf(x01.y, wt, aA.y);
                    aA.z = fmaf(x23.x, wt, aA.z);
                    aA.w = fmaf(x23.y, wt, aA.w);
                    aB.x = fmaf(x45.x, wt, aB.x);
                    aB.y = fmaf(x45.y, wt, aB.y);
                    aB.z = fmaf(x67.x, wt, aB.z);
                    aB.w = fmaf(x67.y, wt, aB.w);
                    pk0 = pk1; r0 = r1;
                }
                accA[ni] = aA;
                accB[ni] = aB;
            }
            if (s < S - 1) soft_grid_sync(bar, s, nblk);
        }
    } else {
        // ---- overflow path (not expected at this shape): per-tile, no
        // slicing; arrive at all barriers afterwards so counts match ----
        for (int tb = base; tb < endE; tb += TILE) {
            const int nt = min(TILE, endE - tb);
            if (tid < SPAN) hcnt[tid] = 0;
            __syncthreads();
            for (int j = tid; j < nt; j += 512)
                atomicAdd(&hcnt[stream8[tb + j].y], 1);
            __syncthreads();
            bin_scan(hcnt, nstart, cur, wtot, SPAN);
            for (int j = tid; j < nt; j += 512) {
                uint2 r = stream8[tb + j];
                int slot = atomicAdd(&cur[(int)r.y], 1);
                srt[slot] = r.x;
            }
            __syncthreads();
            #pragma unroll
            for (int ni = 0; ni < 4; ++ni) {
                int bin = crew + (ni << 5);
                int sB = nstart[bin];
                int e = cur[bin];
                float4 aA = accA[ni];
                float4 aB = accB[ni];
                int k0 = sB + sub;
                unsigned int pk0 = (k0 < e) ? srt[k0] : 0u;
                uint4 r0 = *reinterpret_cast<const uint4*>(
                    emb16b + ((pk0 >> 15) * 128u + qlo));
                for (int k = k0; k < e; k += 2) {
                    int k1 = k + 2;
                    unsigned int pk1 = (k1 < e) ? srt[k1] : 0u;
                    uint4 r1 = *reinterpret_cast<const uint4*>(
                        emb16b + ((pk1 >> 15) * 128u + qlo));
                    float wt = h15_to_float(pk0 & 0x7FFFu);
                    float2 x01 = __half22float2(*reinterpret_cast<__half2*>(&r0.x));
                    float2 x23 = __half22float2(*reinterpret_cast<__half2*>(&r0.y));
                    float2 x45 = __half22float2(*reinterpret_cast<__half2*>(&r0.z));
                    float2 x67 = __half22float2(*reinterpret_cast<__half2*>(&r0.w));
                    aA.x = fmaf(x01.x, wt, aA.x);
                    aA.y = fmaf(x01.y, wt, aA.y);
                    aA.z = fmaf(x23.x, wt, aA.z);
                    aA.w = fmaf(x23.y, wt, aA.w);
                    aB.x = fmaf(x45.x, wt, aB.x);
                    aB.y = fmaf(x45.y, wt, aB.y);
                    aB.z = fmaf(x67.x, wt, aB.z);
                    aB.w = fmaf(x67.y, wt, aB.w);
                    pk0 = pk1; r0 = r1;
                }
                accA[ni] = aA;
                accB[ni] = aB;
            }
            __syncthreads();
        }
        for (int s = 0; s < S - 1; ++s) soft_grid_sync(bar, s, nblk);
    }

    // merge substreams, normalize, write (R6 epilogue)
    #pragma unroll
    for (int ni = 0; ni < 4; ++ni) {
        accA[ni].x += __shfl_xor(accA[ni].x, 8, 64);
        accA[ni].y += __shfl_xor(accA[ni].y, 8, 64);
        accA[ni].z += __shfl_xor(accA[ni].z, 8, 64);
        accA[ni].w += __shfl_xor(accA[ni].w, 8, 64);
        accB[ni].x += __shfl_xor(accB[ni].x, 8, 64);
        accB[ni].y += __shfl_xor(accB[ni].y, 8, 64);
        accB[ni].z += __shfl_xor(accB[ni].z, 8, 64);
        accB[ni].w += __shfl_xor(accB[ni].w, 8, 64);
        int node = g * SPAN + crew + (ni << 5);
        float4 aA = accA[ni];
        float4 aB = accB[ni];
        float ss = aA.x * aA.x + aA.y * aA.y + aA.z * aA.z + aA.w * aA.w
                 + aB.x * aB.x + aB.y * aB.y + aB.z * aB.z + aB.w * aB.w;
        ss += __shfl_xor(ss, 1, 64);
        ss += __shfl_xor(ss, 2, 64);
        ss += __shfl_xor(ss, 4, 64);
        float scale = 1.0f / fmaxf(sqrtf(ss), 1e-12f);
        if (node < N) {
            float4 a = sub ? aB : aA;
            float4 o = make_float4(a.x * scale, a.y * scale,
                                   a.z * scale, a.w * scale);
            *reinterpret_cast<float4*>(out + (size_t)node * EMB_D
                                       + (sl << 3) + (sub << 2)) = o;
        }
    }
}

// --- GF: unsliced fused gather (Tier A6 fallback, proven) -----------------
__global__ __launch_bounds__(512) void gather_fused(
        const char* __restrict__ emb16b,
        const uint2* __restrict__ stream8,
        const int* __restrict__ scanT,
        float* __restrict__ out, int N, int SN) {
    __shared__ uint2 lrec[TILE];
    __shared__ unsigned int srt[TILE];
    __shared__ int hcnt[SPAN];
    __shared__ int nstart[SPAN];
    __shared__ int cur[SPAN];
    __shared__ int wtot[2];

    const int g = blockIdx.x;
    const int tid = threadIdx.x;
    const int lane = tid & 63, wv = tid >> 6;
    const int base = scanT[(size_t)g * SN];
    const int endE = scanT[(size_t)(g + 1) * SN];
    const int crew = tid >> 4;
    const int ql = tid & 15;
    const int sub = ql >> 3;
    const int sl = ql & 7;
    const unsigned qlo = (unsigned)(sl << 4);

    float4 accA[4], accB[4];
    #pragma unroll
    for (int ni = 0; ni < 4; ++ni) {
        accA[ni] = make_float4(0.f, 0.f, 0.f, 0.f);
        accB[ni] = make_float4(0.f, 0.f, 0.f, 0.f);
    }

    for (int tb = base; tb < endE; tb += TILE) {
        const int n = min(TILE, endE - tb);
        if (tid < SPAN) hcnt[tid] = 0;
        __syncthreads();
        for (int j = tid; j < n; j += 512) {
            uint2 r = stream8[tb + j];
            lrec[j] = r;
            atomicAdd(&hcnt[r.y], 1);
        }
        __syncthreads();
        int v = (tid < SPAN) ? hcnt[tid] : 0;
        int x = v;
        #pragma unroll
        for (int off = 1; off < 64; off <<= 1) {
            int t = __shfl_up(x, off, 64);
            if (lane >= off) x += t;
        }
        if (wv < 2 && lane == 63) wtot[wv] = x;
        __syncthreads();
        if (tid < SPAN) {
            int excl = x - v + ((wv == 1) ? wtot[0] : 0);
            nstart[tid] = excl;
            cur[tid] = excl;
        }
        __syncthreads();
        for (int j = tid; j < n; j += 512) {
            uint2 r = lrec[j];
            int slot = atomicAdd(&cur[r.y], 1);
            srt[slot] = r.x;
        }
        __syncthreads();
        #pragma unroll
        for (int ni = 0; ni < 4; ++ni) {
            int nd = crew + (ni << 5);
            int s = nstart[nd];
            int e = cur[nd];
            float4 aA = accA[ni];
            float4 aB = accB[ni];
            int k0 = s + sub;
            unsigned int pk0 = (k0 < e) ? srt[k0] : 0u;
            uint4 r0 = *reinterpret_cast<const uint4*>(
                emb16b + ((pk0 >> 15) * 128u + qlo));
            for (int k = k0; k < e; k += 2) {
                int k1 = k + 2;
                unsigned int pk1 = (k1 < e) ? srt[k1] : 0u;
                uint4 r1 = *reinterpret_cast<const uint4*>(
                    emb16b + ((pk1 >> 15) * 128u + qlo));
                float wt = h15_to_float(pk0 & 0x7FFFu);
                float2 x01 = __half22float2(*reinterpret_cast<__half2*>(&r0.x));
                float2 x23 = __half22float2(*reinterpret_cast<__half2*>(&r0.y));
                float2 x45 = __half22float2(*reinterpret_cast<__half2*>(&r0.z));
                float2 x67 = __half22float2(*reinterpret_cast<__half2*>(&r0.w));
                aA.x = fmaf(x01.x, wt, aA.x);
                aA.y = fmaf(x01.y, wt, aA.y);
                aA.z = fmaf(x23.x, wt, aA.z);
                aA.w = fmaf(x23.y, wt, aA.w);
                aB.x = fmaf(x45.x, wt, aB.x);
                aB.y = fmaf(x45.y, wt, aB.y);
                aB.z = fmaf(x67.x, wt, aB.z);
                aB.w = fmaf(x67.y, wt, aB.w);
                pk0 = pk1; r0 = r1;
            }
            accA[ni] = aA;
            accB[ni] = aB;
        }
        __syncthreads();
    }

    #pragma unroll
    for (int ni = 0; ni < 4; ++ni) {
        accA[ni].x += __shfl_xor(accA[ni].x, 8, 64);
        accA[ni].y += __shfl_xor(accA[ni].y, 8, 64);
        accA[ni].z += __shfl_xor(accA[ni].z, 8, 64);
        accA[ni].w += __shfl_xor(accA[ni].w, 8, 64);
        accB[ni].x += __shfl_xor(accB[ni].x, 8, 64);
        accB[ni].y += __shfl_xor(accB[ni].y, 8, 64);
        accB[ni].z += __shfl_xor(accB[ni].z, 8, 64);
        accB[ni].w += __shfl_xor(accB[ni].w, 8, 64);
        int node = g * SPAN + crew + (ni << 5);
        float4 aA = accA[ni];
        float4 aB = accB[ni];
        float ss = aA.x * aA.x + aA.y * aA.y + aA.z * aA.z + aA.w * aA.w
                 + aB.x * aB.x + aB.y * aB.y + aB.z * aB.z + aB.w * aB.w;
        ss += __shfl_xor(ss, 1, 64);
        ss += __shfl_xor(ss, 2, 64);
        ss += __shfl_xor(ss, 4, 64);
        float scale = 1.0f / fmaxf(sqrtf(ss), 1e-12f);
        if (node < N) {
            float4 a = sub ? aB : aA;
            float4 o = make_float4(a.x * scale, a.y * scale,
                                   a.z * scale, a.w * scale);
            *reinterpret_cast<float4*>(out + (size_t)node * EMB_D
                                       + (sl << 3) + (sub << 2)) = o;
        }
    }
}

// ===========================================================================
// Tier C: atomic scatter fallback.
// ===========================================================================
__global__ void lightgcn_scatter(const float* __restrict__ emb,
                                 const float* __restrict__ w,
                                 const int* __restrict__ src,
                                 const int* __restrict__ dst,
                                 float* __restrict__ h, int E) {
    long long t = (long long)blockIdx.x * blockDim.x + threadIdx.x;
    int e = (int)(t >> 4);
    int d = (int)(t & 15) << 2;
    if (e >= E) return;
    int s = src[e]; int v = dst[e]; float wt = w[e];
    const float4 m = *reinterpret_cast<const float4*>(emb + (size_t)s * EMB_D + d);
    float* o = h + (size_t)v * EMB_D + d;
    unsafeAtomicAdd(o + 0, m.x * wt);
    unsafeAtomicAdd(o + 1, m.y * wt);
    unsafeAtomicAdd(o + 2, m.z * wt);
    unsafeAtomicAdd(o + 3, m.w * wt);
}

__global__ void lightgcn_normalize(float* __restrict__ h, int N) {
    int row = blockIdx.x * (blockDim.x >> 6) + (threadIdx.x >> 6);
    int lane = threadIdx.x & 63;
    if (row >= N) return;
    float x = h[(size_t)row * EMB_D + lane];
    float ss = x * x;
    #pragma unroll
    for (int off = 32; off > 0; off >>= 1)
        ss += __shfl_xor(ss, off, 64);
    h[(size_t)row * EMB_D + lane] = x / fmaxf(sqrtf(ss), 1e-12f);
}

extern "C" void kernel_launch(void* const* d_in, const int* in_sizes, int n_in,
                              void* d_out, int out_size, void* d_ws, size_t ws_size,
                              hipStream_t stream) {
    const float* emb = (const float*)d_in[0];   // [N, 64] fp32
    const float* w   = (const float*)d_in[1];   // [E] fp32
    const int*   src = (const int*)d_in[2];     // [E] int32
    const int*   dst = (const int*)d_in[3];     // [E] int32
    float* out = (float*)d_out;

    const int N = in_sizes[0] / EMB_D;
    const int E = in_sizes[1];
    const int block = 256;
    const int G = (N + SPAN - 1) / SPAN;
    const int S = (N + (1 << SLICE_SH) - 1) >> SLICE_SH;

    const int M3 = G * NCHUNK2;
    const int numB3 = (M3 + SB - 1) / SB;
    const int chunk3 = (E + NCHUNK2 - 1) / NCHUNK2;

    // ---- Tier A8/A6 workspace: cntT[M3] | scanT[M3+1] | partial |
    //      blockoff | bar | pad | stream8[E] uint2 | pad | emb16 ----
    size_t intsA = (size_t)M3 + (size_t)(M3 + 1) + 2 * (size_t)numB3 + 1;
    size_t strOff = (intsA * sizeof(int) + 15) & ~(size_t)15;
    size_t embOff = (strOff + (size_t)E * sizeof(uint2) + 15) & ~(size_t)15;
    size_t needed = embOff + (size_t)N * EMB_D * sizeof(__half);

    if (ws_size >= needed && G <= MAXG && chunk3 <= CHMAX &&
        E < (1 << 28) && N < (1 << 17)) {
        int* cntT     = (int*)d_ws;              // M3
        int* scanT    = cntT + M3;               // M3+1
        int* partial  = scanT + M3 + 1;          // numB3
        int* blockoff = partial + numB3;         // numB3
        int* bar      = blockoff + numB3;        // 1
        uint2* stream8 = (uint2*)((char*)d_ws + strOff);   // E
        __half2* emb16 = (__half2*)((char*)d_ws + embOff);

        int n2 = N * (EMB_D / 2);

        hipMemsetAsync(bar, 0, sizeof(int), stream);

        a1_cast_hist<<<CAST_BLOCKS + NCHUNK2, block, 0, stream>>>(
            (const float2*)emb, emb16, n2, dst, cntT, E, G, chunk3);

        scan_reduceB<<<numB3, SB, 0, stream>>>(cntT, partial, M3);
        scan_partials<<<1, SB, 0, stream>>>(partial, blockoff, scanT, numB3, M3);
        scan_applyB<<<numB3, SB, 0, stream>>>(cntT, blockoff, scanT, M3);

        partition_sort<<<NCHUNK2, 512, 0, stream>>>(src, dst, w, cntT, scanT,
                                                    stream8, E, G, chunk3);

        if (S <= MAXS) {
            gather_sliced<<<G, 512, 0, stream>>>((const char*)emb16, stream8,
                                                 scanT, out, N, S, bar);
        } else {
            gather_fused<<<G, 512, 0, stream>>>((const char*)emb16, stream8,
                                                scanT, out, N, NCHUNK2);
        }
    } else {
        hipMemsetAsync(d_out, 0, (size_t)out_size * sizeof(float), stream);
        long long total = (long long)E * 16;
        int grid = (int)((total + block - 1) / block);
        lightgcn_scatter<<<grid, block, 0, stream>>>(emb, w, src, dst, out, E);
        int gridN = (N + 3) / 4;
        lightgcn_normalize<<<gridN, 256, 0, stream>>>(out, N);
    }
}